// Round 2
// baseline (1939.568 us; speedup 1.0000x reference)
//
#include <hip/hip_runtime.h>
#include <hip/hip_cooperative_groups.h>

namespace cg = cooperative_groups;

// approxmatch EMD (Fan et al.) on MI355X, B=4, N=M=4096, layout (B,3,N).
// Round 8: launch-gap round.
// R1 post-mortem: kernel-time models sum to ~200us but wall is 527us ->
// ~300us is 22 sequential sub-15us launches (inter-dispatch gaps). Culling
// under-delivered because it sits after the LDS read + distance calc.
// Fixes:
//  - ONE cooperative kernel, 21 cg::grid().sync()s replace 21 launch gaps.
//    Phase math verbatim from R1 (same per-row column order -> same sums).
//  - RPW 8 (grid 512 = 2 blocks/CU co-resident, LDS 20.5KB/block): LDS port
//    per cost pass 9.6 -> 4.8us, below the ~12-15us trans-op compute floor.
//  - Fallback multi-launch path (same phase functions) if coop unsupported.

#define NPTS 4096
#define BATCH 4
#define EMD_EPS 1e-9f
#define TILE 1024        // columns staged per LDS stage
#define RPW 8            // rows per wave, in registers
#define THREADS 256      // 4 waves
#define RPB 32           // rows per block = 4 waves * RPW
#define NBLK (NPTS / RPB)  // 128 row-blocks per batch

#define CULL_FULL -160.0f  // exp2(x) == +0.0f for all x < -160
#define CULL_PART -40.0f   // ((2^x)^2)^2 == +0.0f for all x < -40

typedef float v2f __attribute__((ext_vector_type(2)));

struct Params {
    const float* xyz1;
    const float* xyz2;
    float* remainL;
    float* remainR;
    float* ratioL;
    float* ratioR;
    float* cost_part;
    float* S_L;
    float* out;
    float ls2[10];
};

struct Smem {
    float4 sA[TILE / 2];
    float4 sB[TILE / 2];
    float2 sC[TILE / 2];
    float  s_cost[THREADS / 64];
};

__device__ __forceinline__ float fexp2(float x) {
#if __has_builtin(__builtin_amdgcn_exp2f)
    return __builtin_amdgcn_exp2f(x);
#else
    return exp2f(x);
#endif
}
__device__ __forceinline__ float fsqrt(float x) {
#if __has_builtin(__builtin_amdgcn_sqrtf)
    return __builtin_amdgcn_sqrtf(x);
#else
    return __sqrtf(x);
#endif
}

__device__ __forceinline__ float wave_reduce(float v) {
    v += __shfl_xor(v, 32);
    v += __shfl_xor(v, 16);
    v += __shfl_xor(v, 8);
    v += __shfl_xor(v, 4);
    v += __shfl_xor(v, 2);
    v += __shfl_xor(v, 1);
    return v;
}

// ---------------------------------------------------------------- phase: sweep-0 ratioL
// remainR == 1, so ratioL_k = 1/(EPS + sum_l exp2(ls2*d)); inits remainL/R.
__device__ __forceinline__ void phase_ratioL0(Smem& sm, const Params& p, float ls2) {
    const int b = blockIdx.y;
    const int tid = threadIdx.x;
    const int wave = tid >> 6;
    const int lane = tid & 63;
    const int row0 = blockIdx.x * RPB + wave * RPW;

    const float* x1 = p.xyz1 + b * 3 * NPTS;
    const float* x2 = p.xyz2 + b * 3 * NPTS;
    const float2* x2x = (const float2*)(x2);
    const float2* x2y = (const float2*)(x2 + NPTS);
    const float2* x2z = (const float2*)(x2 + 2 * NPTS);

    float px[RPW], py[RPW], pz[RPW];
    v2f acc[RPW];
#pragma unroll
    for (int r = 0; r < RPW; ++r) {
        px[r] = x1[row0 + r];
        py[r] = x1[NPTS + row0 + r];
        pz[r] = x1[2 * NPTS + row0 + r];
        acc[r] = (v2f)(0.0f);
    }
    for (int c0 = 0; c0 < NPTS; c0 += TILE) {
        __syncthreads();
        for (int i = tid; i < TILE / 2; i += THREADS) {
            int e = c0 / 2 + i;
            float2 xx = x2x[e], yy = x2y[e];
            sm.sA[i] = make_float4(xx.x, xx.y, yy.x, yy.y);
            sm.sC[i] = x2z[e];
        }
        __syncthreads();
#pragma unroll 2
        for (int j = 0; j < TILE / 128; ++j) {
            float4 a = sm.sA[lane + 64 * j];
            float2 z = sm.sC[lane + 64 * j];
            v2f ax = {a.x, a.y}, ay = {a.z, a.w}, az = {z.x, z.y};
#pragma unroll
            for (int r = 0; r < RPW; ++r) {
                v2f dx = px[r] - ax, dy = py[r] - ay, dz = pz[r] - az;
                v2f d = dx * dx + dy * dy + dz * dz;
                v2f sd = ls2 * d;
                if (!__all(fmaxf(sd.x, sd.y) < CULL_FULL)) {
                    v2f e2 = {fexp2(sd.x), fexp2(sd.y)};
                    acc[r] += e2;
                }
            }
        }
    }
#pragma unroll
    for (int r = 0; r < RPW; ++r) {
        float s = wave_reduce(acc[r].x + acc[r].y);
        if (lane == 0) {
            int idx = b * NPTS + row0 + r;
            p.ratioL[idx] = 1.0f / (EMD_EPS + s);
            p.remainL[idx] = 1.0f;
            p.remainR[idx] = 1.0f;
        }
    }
}

// ---------------------------------------------------------------- phase: ratioR
template <bool CULL>
__device__ __forceinline__ void phase_ratioR(Smem& sm, const Params& p, float ls2) {
    const int b = blockIdx.y;
    const int tid = threadIdx.x;
    const int wave = tid >> 6;
    const int lane = tid & 63;
    const int col0 = blockIdx.x * RPB + wave * RPW;

    const float* x1 = p.xyz1 + b * 3 * NPTS;
    const float* x2 = p.xyz2 + b * 3 * NPTS;
    const float2* x1x = (const float2*)(x1);
    const float2* x1y = (const float2*)(x1 + NPTS);
    const float2* x1z = (const float2*)(x1 + 2 * NPTS);
    const float2* wLv = (const float2*)(p.ratioL + b * NPTS);

    float px[RPW], py[RPW], pz[RPW];
    v2f acc[RPW];
#pragma unroll
    for (int r = 0; r < RPW; ++r) {
        px[r] = x2[col0 + r];
        py[r] = x2[NPTS + col0 + r];
        pz[r] = x2[2 * NPTS + col0 + r];
        acc[r] = (v2f)(0.0f);
    }
    for (int c0 = 0; c0 < NPTS; c0 += TILE) {
        __syncthreads();
        for (int i = tid; i < TILE / 2; i += THREADS) {
            int e = c0 / 2 + i;
            float2 xx = x1x[e], yy = x1y[e], zz = x1z[e], ww = wLv[e];
            sm.sA[i] = make_float4(xx.x, xx.y, yy.x, yy.y);
            sm.sB[i] = make_float4(zz.x, zz.y, ww.x, ww.y);
        }
        __syncthreads();
#pragma unroll 2
        for (int j = 0; j < TILE / 128; ++j) {
            float4 a = sm.sA[lane + 64 * j];
            float4 bq = sm.sB[lane + 64 * j];
            v2f ax = {a.x, a.y}, ay = {a.z, a.w};
            v2f az = {bq.x, bq.y}, aw = {bq.z, bq.w};
#pragma unroll
            for (int r = 0; r < RPW; ++r) {
                v2f dx = px[r] - ax, dy = py[r] - ay, dz = pz[r] - az;
                v2f d = dx * dx + dy * dy + dz * dz;
                v2f sd = ls2 * d;
                bool live = true;
                if (CULL) live = !__all(fmaxf(sd.x, sd.y) < CULL_FULL);
                if (live) {
                    v2f e2 = {fexp2(sd.x), fexp2(sd.y)};
                    acc[r] += e2 * aw;
                }
            }
        }
    }
#pragma unroll
    for (int r = 0; r < RPW; ++r) {
        float s = wave_reduce(acc[r].x + acc[r].y);
        if (lane == 0) {
            int idx = b * NPTS + col0 + r;
            float rv = p.remainR[idx];
            float sumr = rv * s;
            float cons = fminf(rv / (sumr + EMD_EPS), 1.0f);
            p.ratioR[idx] = cons * rv;
            p.remainR[idx] = fmaxf(0.0f, rv - sumr);
        }
    }
}

// ---------------------------------------------------------------- phase: cost(t) + ratioL(t+1)
// SQ: e2 = exp2(ls2n*d); er = e2^4 * ratioR (ls2 == 4*ls2n exactly).
// !SQ (t=8): er = exp2(ls2*d)*ratioR, e2 == 1.
template <bool SQ, bool CULL>
__device__ __forceinline__ void phase_cost(Smem& sm, const Params& p,
                                           float ls2, float ls2n, int initCost) {
    const int b = blockIdx.y;
    const int tid = threadIdx.x;
    const int wave = tid >> 6;
    const int lane = tid & 63;
    const int row0 = blockIdx.x * RPB + wave * RPW;

    const float* x1 = p.xyz1 + b * 3 * NPTS;
    const float* x2 = p.xyz2 + b * 3 * NPTS;
    const float2* x2x = (const float2*)(x2);
    const float2* x2y = (const float2*)(x2 + NPTS);
    const float2* x2z = (const float2*)(x2 + 2 * NPTS);
    const float2* wRv = (const float2*)(p.ratioR + b * NPTS);
    const float2* w2v = (const float2*)(p.remainR + b * NPTS);

    float px[RPW], py[RPW], pz[RPW];
    v2f acc_a[RPW], acc_c[RPW], acc_s[RPW];
#pragma unroll
    for (int r = 0; r < RPW; ++r) {
        px[r] = x1[row0 + r];
        py[r] = x1[NPTS + row0 + r];
        pz[r] = x1[2 * NPTS + row0 + r];
        acc_a[r] = (v2f)(0.0f);
        acc_c[r] = (v2f)(0.0f);
        acc_s[r] = (v2f)(0.0f);
    }
    for (int c0 = 0; c0 < NPTS; c0 += TILE) {
        __syncthreads();
        for (int i = tid; i < TILE / 2; i += THREADS) {
            int e = c0 / 2 + i;
            float2 xx = x2x[e], yy = x2y[e], zz = x2z[e], wr = wRv[e];
            sm.sA[i] = make_float4(xx.x, xx.y, yy.x, yy.y);
            sm.sB[i] = make_float4(zz.x, zz.y, wr.x, wr.y);
            sm.sC[i] = w2v[e];
        }
        __syncthreads();
#pragma unroll 2
        for (int j = 0; j < TILE / 128; ++j) {
            float4 a = sm.sA[lane + 64 * j];
            float4 bq = sm.sB[lane + 64 * j];
            float2 c = sm.sC[lane + 64 * j];
            v2f ax = {a.x, a.y}, ay = {a.z, a.w};
            v2f az = {bq.x, bq.y}, wr = {bq.z, bq.w};
            v2f cw = {c.x, c.y};
#pragma unroll
            for (int r = 0; r < RPW; ++r) {
                v2f dx = px[r] - ax, dy = py[r] - ay, dz = pz[r] - az;
                v2f d = dx * dx + dy * dy + dz * dz;
                if (SQ) {
                    v2f sd = ls2n * d;
                    bool fullskip = false, partskip = false;
                    if (CULL) {
                        float mx = fmaxf(sd.x, sd.y);
                        fullskip = __all(mx < CULL_FULL);
                        partskip = __all(mx < CULL_PART);
                    }
                    if (!fullskip) {
                        v2f e2 = {fexp2(sd.x), fexp2(sd.y)};
                        acc_s[r] += e2 * cw;
                        if (!partskip) {
                            v2f e4 = e2 * e2;
                            v2f er = (e4 * e4) * wr;
                            acc_a[r] += er;
                            v2f sq = {fsqrt(d.x), fsqrt(d.y)};
                            acc_c[r] += er * sq;
                        }
                    }
                } else {
                    v2f sd = ls2 * d;
                    v2f e1 = {fexp2(sd.x), fexp2(sd.y)};
                    v2f er = e1 * wr;
                    acc_s[r] += cw;   // e2 == 1 when ls2n == 0
                    acc_a[r] += er;
                    v2f sq = {fsqrt(d.x), fsqrt(d.y)};
                    acc_c[r] += er * sq;
                }
            }
        }
    }
    float wcost = 0.0f;
#pragma unroll
    for (int r = 0; r < RPW; ++r) {
        float sa = wave_reduce(acc_a[r].x + acc_a[r].y);
        float sc = wave_reduce(acc_c[r].x + acc_c[r].y);
        float ss = wave_reduce(acc_s[r].x + acc_s[r].y);
        if (lane == 0) {
            int idx = b * NPTS + row0 + r;
            float rl = p.ratioL[idx];
            float rem = fmaxf(0.0f, p.remainL[idx] - rl * sa);
            p.remainL[idx] = rem;
            p.ratioL[idx] = rem / (EMD_EPS + ss);   // next sweep's ratioL
            wcost = fmaf(rl, sc, wcost);
        }
    }
    if (lane == 0) sm.s_cost[wave] = wcost;
    __syncthreads();
    if (tid == 0) {
        float t = sm.s_cost[0] + sm.s_cost[1] + sm.s_cost[2] + sm.s_cost[3];
        int ci = b * NBLK + blockIdx.x;
        p.cost_part[ci] = (initCost ? t : p.cost_part[ci] + t);
    }
}

// ---------------------------------------------------------------- phase: sum ratioL (level 0)
__device__ __forceinline__ void phase_sum_ratioL(Smem& sm, const Params& p) {
    if (blockIdx.x != 0) return;
    const int b = blockIdx.y;
    const int tid = threadIdx.x;
    float s = 0.0f;
    for (int i = tid; i < NPTS; i += 256) s += p.ratioL[b * NPTS + i];
    s = wave_reduce(s);
    if ((tid & 63) == 0) sm.s_cost[tid >> 6] = s;
    __syncthreads();
    if (tid == 0) p.S_L[b] = sm.s_cost[0] + sm.s_cost[1] + sm.s_cost[2] + sm.s_cost[3];
}

// ---------------------------------------------------------------- phase: level-0 cost
__device__ __forceinline__ void phase_cost_l0(Smem& sm, const Params& p) {
    const int b = blockIdx.y;
    const int tid = threadIdx.x;
    const int wave = tid >> 6;
    const int lane = tid & 63;
    const int row0 = blockIdx.x * RPB + wave * RPW;
    const float sL = p.S_L[b];

    const float* x1 = p.xyz1 + b * 3 * NPTS;
    const float* x2 = p.xyz2 + b * 3 * NPTS;
    const float2* x2x = (const float2*)(x2);
    const float2* x2y = (const float2*)(x2 + NPTS);
    const float2* x2z = (const float2*)(x2 + 2 * NPTS);
    const float2* wRv = (const float2*)(p.remainR + b * NPTS);

    float px[RPW], py[RPW], pz[RPW];
    v2f acc_c[RPW];
#pragma unroll
    for (int r = 0; r < RPW; ++r) {
        px[r] = x1[row0 + r];
        py[r] = x1[NPTS + row0 + r];
        pz[r] = x1[2 * NPTS + row0 + r];
        acc_c[r] = (v2f)(0.0f);
    }
    for (int c0 = 0; c0 < NPTS; c0 += TILE) {
        __syncthreads();
        for (int i = tid; i < TILE / 2; i += THREADS) {
            int e = c0 / 2 + i;
            float2 xx = x2x[e], yy = x2y[e], zz = x2z[e], rv = wRv[e];
            // ratioR_l0 inline: sumr = rv*S_L; wr = min(rv/(sumr+eps),1)*rv
            float wr0 = fminf(rv.x / (rv.x * sL + EMD_EPS), 1.0f) * rv.x;
            float wr1 = fminf(rv.y / (rv.y * sL + EMD_EPS), 1.0f) * rv.y;
            sm.sA[i] = make_float4(xx.x, xx.y, yy.x, yy.y);
            sm.sB[i] = make_float4(zz.x, zz.y, wr0, wr1);
        }
        __syncthreads();
#pragma unroll 2
        for (int j = 0; j < TILE / 128; ++j) {
            float4 a = sm.sA[lane + 64 * j];
            float4 bq = sm.sB[lane + 64 * j];
            v2f ax = {a.x, a.y}, ay = {a.z, a.w};
            v2f az = {bq.x, bq.y}, wr = {bq.z, bq.w};
#pragma unroll
            for (int r = 0; r < RPW; ++r) {
                v2f dx = px[r] - ax, dy = py[r] - ay, dz = pz[r] - az;
                v2f d = dx * dx + dy * dy + dz * dz;
                v2f sq = {fsqrt(d.x), fsqrt(d.y)};
                acc_c[r] += wr * sq;
            }
        }
    }
    float wcost = 0.0f;
#pragma unroll
    for (int r = 0; r < RPW; ++r) {
        float sc = wave_reduce(acc_c[r].x + acc_c[r].y);
        if (lane == 0)
            wcost = fmaf(p.ratioL[b * NPTS + row0 + r], sc, wcost);
    }
    if (lane == 0) sm.s_cost[wave] = wcost;
    __syncthreads();
    if (tid == 0) {
        float t = sm.s_cost[0] + sm.s_cost[1] + sm.s_cost[2] + sm.s_cost[3];
        p.cost_part[b * NBLK + blockIdx.x] += t;
    }
}

// ---------------------------------------------------------------- phase: finalize
__device__ __forceinline__ void phase_final(Smem& sm, const Params& p) {
    if (blockIdx.x != 0 || blockIdx.y != 0) return;
    const int tid = threadIdx.x;
    float s = 0.0f;
    for (int i = tid; i < BATCH * NBLK; i += 256) s += p.cost_part[i];
    s = wave_reduce(s);
    if ((tid & 63) == 0) sm.s_cost[tid >> 6] = s;
    __syncthreads();
    if (tid == 0)
        p.out[0] = (sm.s_cost[0] + sm.s_cost[1] + sm.s_cost[2] + sm.s_cost[3]) /
                   ((float)NPTS * (float)BATCH);
}

// ---------------------------------------------------------------- unified cooperative kernel
__global__ __launch_bounds__(THREADS, 2) void k_emd_all(Params p) {
    cg::grid_group g = cg::this_grid();
    __shared__ Smem sm;

    phase_ratioL0(sm, p, p.ls2[0]);
    g.sync();
    for (int t = 0; t < 9; ++t) {
        if (t < 3) phase_ratioR<true>(sm, p, p.ls2[t]);
        else       phase_ratioR<false>(sm, p, p.ls2[t]);
        g.sync();
        if (t < 3)      phase_cost<true, true>(sm, p, p.ls2[t], p.ls2[t + 1], t == 0);
        else if (t < 8) phase_cost<true, false>(sm, p, p.ls2[t], p.ls2[t + 1], 0);
        else            phase_cost<false, false>(sm, p, p.ls2[8], 0.0f, 0);
        g.sync();
    }
    phase_sum_ratioL(sm, p);
    g.sync();
    phase_cost_l0(sm, p);
    g.sync();
    phase_final(sm, p);
}

// ---------------------------------------------------------------- fallback wrappers
__global__ __launch_bounds__(THREADS, 2) void kw_ratioL0(Params p) {
    __shared__ Smem sm;
    phase_ratioL0(sm, p, p.ls2[0]);
}
__global__ __launch_bounds__(THREADS, 2) void kw_ratioR(Params p, int t) {
    __shared__ Smem sm;
    if (t < 3) phase_ratioR<true>(sm, p, p.ls2[t]);
    else       phase_ratioR<false>(sm, p, p.ls2[t]);
}
__global__ __launch_bounds__(THREADS, 2) void kw_cost(Params p, int t) {
    __shared__ Smem sm;
    if (t < 3)      phase_cost<true, true>(sm, p, p.ls2[t], p.ls2[t + 1], t == 0);
    else if (t < 8) phase_cost<true, false>(sm, p, p.ls2[t], p.ls2[t + 1], 0);
    else            phase_cost<false, false>(sm, p, p.ls2[8], 0.0f, 0);
}
__global__ __launch_bounds__(THREADS, 2) void kw_sum(Params p) {
    __shared__ Smem sm;
    phase_sum_ratioL(sm, p);
}
__global__ __launch_bounds__(THREADS, 2) void kw_cost_l0(Params p) {
    __shared__ Smem sm;
    phase_cost_l0(sm, p);
}
__global__ __launch_bounds__(THREADS, 2) void kw_final(Params p) {
    __shared__ Smem sm;
    phase_final(sm, p);
}

extern "C" void kernel_launch(void* const* d_in, const int* in_sizes, int n_in,
                              void* d_out, int out_size, void* d_ws, size_t ws_size,
                              hipStream_t stream) {
    Params p;
    p.xyz1 = (const float*)d_in[0];
    p.xyz2 = (const float*)d_in[1];
    const int BN = BATCH * NPTS;
    float* ws = (float*)d_ws;
    p.remainL   = ws;                       // BN
    p.remainR   = ws + 1 * BN;              // BN
    p.ratioL    = ws + 2 * BN;              // BN
    p.ratioR    = ws + 3 * BN;              // BN
    p.cost_part = ws + 4 * BN;              // BATCH*NBLK = 512
    p.S_L       = p.cost_part + BATCH * NBLK;  // BATCH
    p.out       = (float*)d_out;

    // levels: -(4^j) for j = 7..-1, then 0; premultiplied by log2(e) in
    // double then truncated (bitwise identical to previous rounds).
    static const double levels[10] = {
        -16384.0, -4096.0, -1024.0, -256.0, -64.0,
        -16.0, -4.0, -1.0, -0.25, 0.0};
    for (int t = 0; t < 10; ++t)
        p.ls2[t] = (float)(levels[t] * 1.4426950408889634);

    dim3 grid(NBLK, BATCH), blk(THREADS);

    static int coop_ok = -1;
    if (coop_ok < 0) {
        int v = 0;
        hipDeviceGetAttribute(&v, hipDeviceAttributeCooperativeLaunch, 0);
        coop_ok = v;
    }

    hipError_t err = hipErrorUnknown;
    if (coop_ok) {
        void* args[] = {(void*)&p};
        err = hipLaunchCooperativeKernel((void*)k_emd_all, grid, blk, args, 0, stream);
    }
    if (err != hipSuccess) {
        kw_ratioL0<<<grid, blk, 0, stream>>>(p);
        for (int t = 0; t < 9; ++t) {
            kw_ratioR<<<grid, blk, 0, stream>>>(p, t);
            kw_cost<<<grid, blk, 0, stream>>>(p, t);
        }
        kw_sum<<<dim3(1, BATCH), blk, 0, stream>>>(p);
        kw_cost_l0<<<grid, blk, 0, stream>>>(p);
        kw_final<<<dim3(1, 1), blk, 0, stream>>>(p);
    }
}

// Round 3
// 1552.938 us; speedup vs baseline: 1.2490x; 1.2490x over previous
//
#include <hip/hip_runtime.h>

// approxmatch EMD (Fan et al.) on MI355X, B=4, N=M=4096, layout (B,3,N).
// Round 9: coherence round.
// R2 post-mortem: cg::grid().sync() = agent acquire/release = L2 writeback +
// invalidate per sync on multi-XCD -> 157MB re-fetch, 17% VALUBusy, 1939us.
// Fix: all mutable cross-block state (ratioL/ratioR/remainL/remainR/cost_part/
// S_L) accessed ONLY via relaxed agent-scope atomics (bypass non-coherent L2,
// served at LLC). Read-only xyz stays L2-cached across all phases. The grid
// barrier is then just a relaxed agent atomicAdd + relaxed spin + compiler
// fence: no cache maintenance instructions at all. __syncthreads() before the
// arrive already drains vmcnt for every wave -> stores are at LLC.
// Geometry back to R1-proven: RPW=4, 1024 blocks = 4/CU (16 waves/CU);
// TILE 512 -> Smem 10.3KB so any occupancy calc grants 4 blocks/CU.
// CULL extended to t=3 (~50% partskip at ls2n=-92). Multi-launch fallback
// if coop launch is rejected.

#define NPTS 4096
#define BATCH 4
#define EMD_EPS 1e-9f
#define TILE 512         // columns staged per LDS stage
#define RPW 4            // rows per wave, in registers
#define THREADS 256      // 4 waves
#define RPB 16           // rows per block = 4 waves * RPW
#define NBLK (NPTS / RPB)          // 256 row-blocks per batch
#define NBLK_TOTAL (NBLK * BATCH)  // 1024 blocks = 4 per CU

#define CULL_FULL -160.0f  // exp2(x) == +0.0f for all x < -160
#define CULL_PART -40.0f   // ((2^x)^2)^2 == +0.0f for all x < -40

typedef float v2f __attribute__((ext_vector_type(2)));

struct Params {
    const float* xyz1;
    const float* xyz2;
    float* remainL;
    float* remainR;
    float* ratioL;
    float* ratioR;
    float* cost_part;
    float* S_L;
    float* out;
    unsigned* bar;
    float ls2[10];
};

struct Smem {
    float4 sA[TILE / 2];
    float4 sB[TILE / 2];
    float2 sC[TILE / 2];
    float  s_cost[THREADS / 64];
};

// ---------------- agent-scope (LLC-coherent, L2-bypassing) accessors.
// Relaxed => no compiler-inserted cache maintenance (no buffer_inv/wbl2);
// the op itself is routed past the non-coherent per-XCD L2.
__device__ __forceinline__ float aload(const float* p_) {
    return __hip_atomic_load((float*)p_, __ATOMIC_RELAXED, __HIP_MEMORY_SCOPE_AGENT);
}
__device__ __forceinline__ v2f aload2(const float* p_) {
    unsigned long long u = __hip_atomic_load((unsigned long long*)p_,
                                             __ATOMIC_RELAXED, __HIP_MEMORY_SCOPE_AGENT);
    v2f f;
    f.x = __uint_as_float((unsigned)u);
    f.y = __uint_as_float((unsigned)(u >> 32));
    return f;
}
__device__ __forceinline__ void astore(float* p_, float v) {
    __hip_atomic_store(p_, v, __ATOMIC_RELAXED, __HIP_MEMORY_SCOPE_AGENT);
}

// ---------------- grid barrier, no cache maintenance.
// __syncthreads() drains vmcnt per wave -> this block's agent stores are at
// the LLC before thread 0 arrives. Other blocks' stores likewise precede
// their arrive. Spin reads bypass L2 -> observing count==N implies all data
// is visible via agent loads. asm memory clobber stops compiler hoisting.
__device__ __forceinline__ void gsync(unsigned* bar, int idx) {
    __syncthreads();
    if (threadIdx.x == 0) {
        __hip_atomic_fetch_add(&bar[idx], 1u, __ATOMIC_RELAXED, __HIP_MEMORY_SCOPE_AGENT);
        while (__hip_atomic_load(&bar[idx], __ATOMIC_RELAXED, __HIP_MEMORY_SCOPE_AGENT)
               < (unsigned)NBLK_TOTAL)
            __builtin_amdgcn_s_sleep(2);
        asm volatile("" ::: "memory");
    }
    __syncthreads();
}

__device__ __forceinline__ float fexp2(float x) {
#if __has_builtin(__builtin_amdgcn_exp2f)
    return __builtin_amdgcn_exp2f(x);
#else
    return exp2f(x);
#endif
}
__device__ __forceinline__ float fsqrt(float x) {
#if __has_builtin(__builtin_amdgcn_sqrtf)
    return __builtin_amdgcn_sqrtf(x);
#else
    return __sqrtf(x);
#endif
}

__device__ __forceinline__ float wave_reduce(float v) {
    v += __shfl_xor(v, 32);
    v += __shfl_xor(v, 16);
    v += __shfl_xor(v, 8);
    v += __shfl_xor(v, 4);
    v += __shfl_xor(v, 2);
    v += __shfl_xor(v, 1);
    return v;
}

// ---------------------------------------------------------------- phase: sweep-0 ratioL
__device__ __forceinline__ void phase_ratioL0(Smem& sm, const Params& p, float ls2) {
    const int b = blockIdx.y;
    const int tid = threadIdx.x;
    const int wave = tid >> 6;
    const int lane = tid & 63;
    const int row0 = blockIdx.x * RPB + wave * RPW;

    const float* x1 = p.xyz1 + b * 3 * NPTS;
    const float* x2 = p.xyz2 + b * 3 * NPTS;
    const float2* x2x = (const float2*)(x2);
    const float2* x2y = (const float2*)(x2 + NPTS);
    const float2* x2z = (const float2*)(x2 + 2 * NPTS);

    float px[RPW], py[RPW], pz[RPW];
    v2f acc[RPW];
#pragma unroll
    for (int r = 0; r < RPW; ++r) {
        px[r] = x1[row0 + r];
        py[r] = x1[NPTS + row0 + r];
        pz[r] = x1[2 * NPTS + row0 + r];
        acc[r] = (v2f)(0.0f);
    }
    for (int c0 = 0; c0 < NPTS; c0 += TILE) {
        __syncthreads();
        for (int i = tid; i < TILE / 2; i += THREADS) {
            int e = c0 / 2 + i;
            float2 xx = x2x[e], yy = x2y[e];
            sm.sA[i] = make_float4(xx.x, xx.y, yy.x, yy.y);
            sm.sC[i] = x2z[e];
        }
        __syncthreads();
#pragma unroll 2
        for (int j = 0; j < TILE / 128; ++j) {
            float4 a = sm.sA[lane + 64 * j];
            float2 z = sm.sC[lane + 64 * j];
            v2f ax = {a.x, a.y}, ay = {a.z, a.w}, az = {z.x, z.y};
#pragma unroll
            for (int r = 0; r < RPW; ++r) {
                v2f dx = px[r] - ax, dy = py[r] - ay, dz = pz[r] - az;
                v2f d = dx * dx + dy * dy + dz * dz;
                v2f sd = ls2 * d;
                if (!__all(fmaxf(sd.x, sd.y) < CULL_FULL)) {
                    v2f e2 = {fexp2(sd.x), fexp2(sd.y)};
                    acc[r] += e2;
                }
            }
        }
    }
#pragma unroll
    for (int r = 0; r < RPW; ++r) {
        float s = wave_reduce(acc[r].x + acc[r].y);
        if (lane == 0) {
            int idx = b * NPTS + row0 + r;
            astore(&p.ratioL[idx], 1.0f / (EMD_EPS + s));
            astore(&p.remainL[idx], 1.0f);
            astore(&p.remainR[idx], 1.0f);
        }
    }
}

// ---------------------------------------------------------------- phase: ratioR
template <bool CULL>
__device__ __forceinline__ void phase_ratioR(Smem& sm, const Params& p, float ls2) {
    const int b = blockIdx.y;
    const int tid = threadIdx.x;
    const int wave = tid >> 6;
    const int lane = tid & 63;
    const int col0 = blockIdx.x * RPB + wave * RPW;

    const float* x1 = p.xyz1 + b * 3 * NPTS;
    const float* x2 = p.xyz2 + b * 3 * NPTS;
    const float2* x1x = (const float2*)(x1);
    const float2* x1y = (const float2*)(x1 + NPTS);
    const float2* x1z = (const float2*)(x1 + 2 * NPTS);
    const float* rL = p.ratioL + b * NPTS;

    float px[RPW], py[RPW], pz[RPW];
    v2f acc[RPW];
#pragma unroll
    for (int r = 0; r < RPW; ++r) {
        px[r] = x2[col0 + r];
        py[r] = x2[NPTS + col0 + r];
        pz[r] = x2[2 * NPTS + col0 + r];
        acc[r] = (v2f)(0.0f);
    }
    for (int c0 = 0; c0 < NPTS; c0 += TILE) {
        __syncthreads();
        for (int i = tid; i < TILE / 2; i += THREADS) {
            int e = c0 / 2 + i;
            float2 xx = x1x[e], yy = x1y[e], zz = x1z[e];
            v2f ww = aload2(rL + 2 * e);
            sm.sA[i] = make_float4(xx.x, xx.y, yy.x, yy.y);
            sm.sB[i] = make_float4(zz.x, zz.y, ww.x, ww.y);
        }
        __syncthreads();
#pragma unroll 2
        for (int j = 0; j < TILE / 128; ++j) {
            float4 a = sm.sA[lane + 64 * j];
            float4 bq = sm.sB[lane + 64 * j];
            v2f ax = {a.x, a.y}, ay = {a.z, a.w};
            v2f az = {bq.x, bq.y}, aw = {bq.z, bq.w};
#pragma unroll
            for (int r = 0; r < RPW; ++r) {
                v2f dx = px[r] - ax, dy = py[r] - ay, dz = pz[r] - az;
                v2f d = dx * dx + dy * dy + dz * dz;
                v2f sd = ls2 * d;
                bool live = true;
                if (CULL) live = !__all(fmaxf(sd.x, sd.y) < CULL_FULL);
                if (live) {
                    v2f e2 = {fexp2(sd.x), fexp2(sd.y)};
                    acc[r] += e2 * aw;
                }
            }
        }
    }
#pragma unroll
    for (int r = 0; r < RPW; ++r) {
        float s = wave_reduce(acc[r].x + acc[r].y);
        if (lane == 0) {
            int idx = b * NPTS + col0 + r;
            float rv = aload(&p.remainR[idx]);
            float sumr = rv * s;
            float cons = fminf(rv / (sumr + EMD_EPS), 1.0f);
            astore(&p.ratioR[idx], cons * rv);
            astore(&p.remainR[idx], fmaxf(0.0f, rv - sumr));
        }
    }
}

// ---------------------------------------------------------------- phase: cost(t) + ratioL(t+1)
template <bool SQ, bool CULL>
__device__ __forceinline__ void phase_cost(Smem& sm, const Params& p,
                                           float ls2, float ls2n, int initCost) {
    const int b = blockIdx.y;
    const int tid = threadIdx.x;
    const int wave = tid >> 6;
    const int lane = tid & 63;
    const int row0 = blockIdx.x * RPB + wave * RPW;

    const float* x1 = p.xyz1 + b * 3 * NPTS;
    const float* x2 = p.xyz2 + b * 3 * NPTS;
    const float2* x2x = (const float2*)(x2);
    const float2* x2y = (const float2*)(x2 + NPTS);
    const float2* x2z = (const float2*)(x2 + 2 * NPTS);
    const float* rR = p.ratioR + b * NPTS;
    const float* w2 = p.remainR + b * NPTS;

    float px[RPW], py[RPW], pz[RPW];
    v2f acc_a[RPW], acc_c[RPW], acc_s[RPW];
#pragma unroll
    for (int r = 0; r < RPW; ++r) {
        px[r] = x1[row0 + r];
        py[r] = x1[NPTS + row0 + r];
        pz[r] = x1[2 * NPTS + row0 + r];
        acc_a[r] = (v2f)(0.0f);
        acc_c[r] = (v2f)(0.0f);
        acc_s[r] = (v2f)(0.0f);
    }
    for (int c0 = 0; c0 < NPTS; c0 += TILE) {
        __syncthreads();
        for (int i = tid; i < TILE / 2; i += THREADS) {
            int e = c0 / 2 + i;
            float2 xx = x2x[e], yy = x2y[e], zz = x2z[e];
            v2f wr = aload2(rR + 2 * e);
            v2f w2v = aload2(w2 + 2 * e);
            sm.sA[i] = make_float4(xx.x, xx.y, yy.x, yy.y);
            sm.sB[i] = make_float4(zz.x, zz.y, wr.x, wr.y);
            sm.sC[i] = make_float2(w2v.x, w2v.y);
        }
        __syncthreads();
#pragma unroll 2
        for (int j = 0; j < TILE / 128; ++j) {
            float4 a = sm.sA[lane + 64 * j];
            float4 bq = sm.sB[lane + 64 * j];
            float2 c = sm.sC[lane + 64 * j];
            v2f ax = {a.x, a.y}, ay = {a.z, a.w};
            v2f az = {bq.x, bq.y}, wr = {bq.z, bq.w};
            v2f cw = {c.x, c.y};
#pragma unroll
            for (int r = 0; r < RPW; ++r) {
                v2f dx = px[r] - ax, dy = py[r] - ay, dz = pz[r] - az;
                v2f d = dx * dx + dy * dy + dz * dz;
                if (SQ) {
                    v2f sd = ls2n * d;
                    bool fullskip = false, partskip = false;
                    if (CULL) {
                        float mx = fmaxf(sd.x, sd.y);
                        fullskip = __all(mx < CULL_FULL);
                        partskip = __all(mx < CULL_PART);
                    }
                    if (!fullskip) {
                        v2f e2 = {fexp2(sd.x), fexp2(sd.y)};
                        acc_s[r] += e2 * cw;
                        if (!partskip) {
                            v2f e4 = e2 * e2;
                            v2f er = (e4 * e4) * wr;
                            acc_a[r] += er;
                            v2f sq = {fsqrt(d.x), fsqrt(d.y)};
                            acc_c[r] += er * sq;
                        }
                    }
                } else {
                    v2f sd = ls2 * d;
                    v2f e1 = {fexp2(sd.x), fexp2(sd.y)};
                    v2f er = e1 * wr;
                    acc_s[r] += cw;   // e2 == 1 when ls2n == 0
                    acc_a[r] += er;
                    v2f sq = {fsqrt(d.x), fsqrt(d.y)};
                    acc_c[r] += er * sq;
                }
            }
        }
    }
    float wcost = 0.0f;
#pragma unroll
    for (int r = 0; r < RPW; ++r) {
        float sa = wave_reduce(acc_a[r].x + acc_a[r].y);
        float sc = wave_reduce(acc_c[r].x + acc_c[r].y);
        float ss = wave_reduce(acc_s[r].x + acc_s[r].y);
        if (lane == 0) {
            int idx = b * NPTS + row0 + r;
            float rl = aload(&p.ratioL[idx]);
            float rem = fmaxf(0.0f, aload(&p.remainL[idx]) - rl * sa);
            astore(&p.remainL[idx], rem);
            astore(&p.ratioL[idx], rem / (EMD_EPS + ss));   // next sweep's ratioL
            wcost = fmaf(rl, sc, wcost);
        }
    }
    if (lane == 0) sm.s_cost[wave] = wcost;
    __syncthreads();
    if (tid == 0) {
        float t = sm.s_cost[0] + sm.s_cost[1] + sm.s_cost[2] + sm.s_cost[3];
        int ci = b * NBLK + blockIdx.x;
        astore(&p.cost_part[ci], initCost ? t : aload(&p.cost_part[ci]) + t);
    }
}

// ---------------------------------------------------------------- phase: sum ratioL (level 0)
__device__ __forceinline__ void phase_sum_ratioL(Smem& sm, const Params& p) {
    if (blockIdx.x != 0) return;
    const int b = blockIdx.y;
    const int tid = threadIdx.x;
    float s = 0.0f;
    for (int i = tid; i < NPTS; i += 256) s += aload(&p.ratioL[b * NPTS + i]);
    s = wave_reduce(s);
    if ((tid & 63) == 0) sm.s_cost[tid >> 6] = s;
    __syncthreads();
    if (tid == 0)
        astore(&p.S_L[b], sm.s_cost[0] + sm.s_cost[1] + sm.s_cost[2] + sm.s_cost[3]);
}

// ---------------------------------------------------------------- phase: level-0 cost
__device__ __forceinline__ void phase_cost_l0(Smem& sm, const Params& p) {
    const int b = blockIdx.y;
    const int tid = threadIdx.x;
    const int wave = tid >> 6;
    const int lane = tid & 63;
    const int row0 = blockIdx.x * RPB + wave * RPW;
    const float sL = aload(&p.S_L[b]);

    const float* x1 = p.xyz1 + b * 3 * NPTS;
    const float* x2 = p.xyz2 + b * 3 * NPTS;
    const float2* x2x = (const float2*)(x2);
    const float2* x2y = (const float2*)(x2 + NPTS);
    const float2* x2z = (const float2*)(x2 + 2 * NPTS);
    const float* w2 = p.remainR + b * NPTS;

    float px[RPW], py[RPW], pz[RPW];
    v2f acc_c[RPW];
#pragma unroll
    for (int r = 0; r < RPW; ++r) {
        px[r] = x1[row0 + r];
        py[r] = x1[NPTS + row0 + r];
        pz[r] = x1[2 * NPTS + row0 + r];
        acc_c[r] = (v2f)(0.0f);
    }
    for (int c0 = 0; c0 < NPTS; c0 += TILE) {
        __syncthreads();
        for (int i = tid; i < TILE / 2; i += THREADS) {
            int e = c0 / 2 + i;
            float2 xx = x2x[e], yy = x2y[e], zz = x2z[e];
            v2f rv = aload2(w2 + 2 * e);
            // ratioR_l0 inline: sumr = rv*S_L; wr = min(rv/(sumr+eps),1)*rv
            float wr0 = fminf(rv.x / (rv.x * sL + EMD_EPS), 1.0f) * rv.x;
            float wr1 = fminf(rv.y / (rv.y * sL + EMD_EPS), 1.0f) * rv.y;
            sm.sA[i] = make_float4(xx.x, xx.y, yy.x, yy.y);
            sm.sB[i] = make_float4(zz.x, zz.y, wr0, wr1);
        }
        __syncthreads();
#pragma unroll 2
        for (int j = 0; j < TILE / 128; ++j) {
            float4 a = sm.sA[lane + 64 * j];
            float4 bq = sm.sB[lane + 64 * j];
            v2f ax = {a.x, a.y}, ay = {a.z, a.w};
            v2f az = {bq.x, bq.y}, wr = {bq.z, bq.w};
#pragma unroll
            for (int r = 0; r < RPW; ++r) {
                v2f dx = px[r] - ax, dy = py[r] - ay, dz = pz[r] - az;
                v2f d = dx * dx + dy * dy + dz * dz;
                v2f sq = {fsqrt(d.x), fsqrt(d.y)};
                acc_c[r] += wr * sq;
            }
        }
    }
    float wcost = 0.0f;
#pragma unroll
    for (int r = 0; r < RPW; ++r) {
        float sc = wave_reduce(acc_c[r].x + acc_c[r].y);
        if (lane == 0)
            wcost = fmaf(aload(&p.ratioL[b * NPTS + row0 + r]), sc, wcost);
    }
    if (lane == 0) sm.s_cost[wave] = wcost;
    __syncthreads();
    if (tid == 0) {
        float t = sm.s_cost[0] + sm.s_cost[1] + sm.s_cost[2] + sm.s_cost[3];
        int ci = b * NBLK + blockIdx.x;
        astore(&p.cost_part[ci], aload(&p.cost_part[ci]) + t);
    }
}

// ---------------------------------------------------------------- phase: finalize
__device__ __forceinline__ void phase_final(Smem& sm, const Params& p) {
    if (blockIdx.x != 0 || blockIdx.y != 0) return;
    const int tid = threadIdx.x;
    float s = 0.0f;
    for (int i = tid; i < BATCH * NBLK; i += 256) s += aload(&p.cost_part[i]);
    s = wave_reduce(s);
    if ((tid & 63) == 0) sm.s_cost[tid >> 6] = s;
    __syncthreads();
    if (tid == 0)
        p.out[0] = (sm.s_cost[0] + sm.s_cost[1] + sm.s_cost[2] + sm.s_cost[3]) /
                   ((float)NPTS * (float)BATCH);
}

// ---------------------------------------------------------------- unified persistent kernel
__global__ __launch_bounds__(THREADS, 4) void k_emd_all(Params p) {
    __shared__ Smem sm;
    int bi = 0;
    phase_ratioL0(sm, p, p.ls2[0]);
    gsync(p.bar, bi++);
    for (int t = 0; t < 9; ++t) {
        if (t < 4) phase_ratioR<true>(sm, p, p.ls2[t]);
        else       phase_ratioR<false>(sm, p, p.ls2[t]);
        gsync(p.bar, bi++);
        if (t < 4)      phase_cost<true, true>(sm, p, p.ls2[t], p.ls2[t + 1], t == 0);
        else if (t < 8) phase_cost<true, false>(sm, p, p.ls2[t], p.ls2[t + 1], 0);
        else            phase_cost<false, false>(sm, p, p.ls2[8], 0.0f, 0);
        gsync(p.bar, bi++);
    }
    phase_sum_ratioL(sm, p);
    gsync(p.bar, bi++);
    phase_cost_l0(sm, p);
    gsync(p.bar, bi++);
    phase_final(sm, p);
}

// ---------------------------------------------------------------- barrier init
__global__ void k_zero(unsigned* bar) {
    if (threadIdx.x < 32)
        __hip_atomic_store(&bar[threadIdx.x], 0u, __ATOMIC_RELAXED, __HIP_MEMORY_SCOPE_AGENT);
}

// ---------------------------------------------------------------- fallback wrappers
__global__ __launch_bounds__(THREADS, 4) void kw_ratioL0(Params p) {
    __shared__ Smem sm;
    phase_ratioL0(sm, p, p.ls2[0]);
}
__global__ __launch_bounds__(THREADS, 4) void kw_ratioR(Params p, int t) {
    __shared__ Smem sm;
    if (t < 4) phase_ratioR<true>(sm, p, p.ls2[t]);
    else       phase_ratioR<false>(sm, p, p.ls2[t]);
}
__global__ __launch_bounds__(THREADS, 4) void kw_cost(Params p, int t) {
    __shared__ Smem sm;
    if (t < 4)      phase_cost<true, true>(sm, p, p.ls2[t], p.ls2[t + 1], t == 0);
    else if (t < 8) phase_cost<true, false>(sm, p, p.ls2[t], p.ls2[t + 1], 0);
    else            phase_cost<false, false>(sm, p, p.ls2[8], 0.0f, 0);
}
__global__ __launch_bounds__(THREADS, 4) void kw_sum(Params p) {
    __shared__ Smem sm;
    phase_sum_ratioL(sm, p);
}
__global__ __launch_bounds__(THREADS, 4) void kw_cost_l0(Params p) {
    __shared__ Smem sm;
    phase_cost_l0(sm, p);
}
__global__ __launch_bounds__(THREADS, 4) void kw_final(Params p) {
    __shared__ Smem sm;
    phase_final(sm, p);
}

extern "C" void kernel_launch(void* const* d_in, const int* in_sizes, int n_in,
                              void* d_out, int out_size, void* d_ws, size_t ws_size,
                              hipStream_t stream) {
    Params p;
    p.xyz1 = (const float*)d_in[0];
    p.xyz2 = (const float*)d_in[1];
    const int BN = BATCH * NPTS;
    float* ws = (float*)d_ws;
    p.remainL   = ws;                       // BN
    p.remainR   = ws + 1 * BN;              // BN
    p.ratioL    = ws + 2 * BN;              // BN
    p.ratioR    = ws + 3 * BN;              // BN
    p.cost_part = ws + 4 * BN;              // BATCH*NBLK = 1024
    p.S_L       = p.cost_part + BATCH * NBLK;  // BATCH
    p.bar       = (unsigned*)(p.S_L + BATCH);  // 32 counters
    p.out       = (float*)d_out;

    static const double levels[10] = {
        -16384.0, -4096.0, -1024.0, -256.0, -64.0,
        -16.0, -4.0, -1.0, -0.25, 0.0};
    for (int t = 0; t < 10; ++t)
        p.ls2[t] = (float)(levels[t] * 1.4426950408889634);

    dim3 grid(NBLK, BATCH), blk(THREADS);

    static int coop_ok = -1;
    if (coop_ok < 0) {
        int v = 0;
        hipDeviceGetAttribute(&v, hipDeviceAttributeCooperativeLaunch, 0);
        coop_ok = v;
    }

    hipError_t err = hipErrorUnknown;
    if (coop_ok) {
        k_zero<<<1, 64, 0, stream>>>(p.bar);
        void* args[] = {(void*)&p};
        err = hipLaunchCooperativeKernel((void*)k_emd_all, grid, blk, args, 0, stream);
    }
    if (err != hipSuccess) {
        kw_ratioL0<<<grid, blk, 0, stream>>>(p);
        for (int t = 0; t < 9; ++t) {
            kw_ratioR<<<grid, blk, 0, stream>>>(p, t);
            kw_cost<<<grid, blk, 0, stream>>>(p, t);
        }
        kw_sum<<<dim3(1, BATCH), blk, 0, stream>>>(p);
        kw_cost_l0<<<grid, blk, 0, stream>>>(p);
        kw_final<<<dim3(1, 1), blk, 0, stream>>>(p);
    }
}

// Round 4
// 653.014 us; speedup vs baseline: 2.9702x; 2.3781x over previous
//
#include <hip/hip_runtime.h>

// approxmatch EMD (Fan et al.) on MI355X, B=4, N=M=4096, layout (B,3,N).
// Round 10: barrier-contention + L2-restore round.
// R3 post-mortem: 1552us wall, VALUBusy 20.7% (~320us work) -> ~1.2ms stall:
//  (a) single-counter grid barrier: 1024 RMWs + 1024 pollers on ONE LLC line
//      (s_sleep(2)) -> ~60us/barrier x21.
//  (b) agent atomics on mutable arrays bypass L2 -> 32MB/phase read at LLC.
// Fixes:
//  (a) two-level barrier: 64 group counters (16 RMWs each) -> root (64 RMWs);
//      leaders poll root, members poll group-release; s_sleep(4).
//  (b) versioned single-assignment buffers per sweep: writes via relaxed agent
//      stores (LLC-visible, R3-proven), reads via NORMAL vectorized loads --
//      fresh addresses can't be L2-stale (launch invalidates L2, no HW
//      prefetch, 4KB pads), first touch fills from LLC, rest hit L2.
//      remainL is block-private -> plain loads/stores, single buffer.
// Geometry unchanged from R3 (RPW=4, 1024 blocks, TILE=512, VGPR 64).

#define NPTS 4096
#define BATCH 4
#define EMD_EPS 1e-9f
#define TILE 512         // columns staged per LDS stage
#define RPW 4            // rows per wave, in registers
#define THREADS 256      // 4 waves
#define RPB 16           // rows per block = 4 waves * RPW
#define NBLK (NPTS / RPB)          // 256 row-blocks per batch
#define NBLK_TOTAL (NBLK * BATCH)  // 1024 blocks = 4 per CU

#define GRP_SHIFT 4
#define GRP_SIZE (1 << GRP_SHIFT)      // 16 blocks per barrier group
#define NGRP (NBLK_TOTAL / GRP_SIZE)   // 64 groups
#define BAR_STRIDE 4352                // u32 per barrier instance
#define NB_BAR 24                      // 21 used

#define CULL_FULL -160.0f  // exp2(x) == +0.0f for all x < -160
#define CULL_PART -40.0f   // ((2^x)^2)^2 == +0.0f for all x < -40

typedef float v2f __attribute__((ext_vector_type(2)));

struct Params {
    const float* xyz1;
    const float* xyz2;
    float* remainL;          // block-private: normal access
    float* cost_part;        // agent (cross-XCD read at finalize)
    float* S_L;              // agent
    float* out;
    unsigned* bar;
    float* ratioL[10];       // versioned: ratioL[t] written end of sweep t-1
    float* ratioR[9];        // versioned per sweep
    float* remainR[9];       // versioned per sweep
    float ls2[10];
};

struct Smem {
    float4 sA[TILE / 2];
    float4 sB[TILE / 2];
    float2 sC[TILE / 2];
    float  s_cost[THREADS / 64];
};

// ---------------- agent-scope (LLC-routed, L2-bypassing) accessors
__device__ __forceinline__ float aload(const float* p_) {
    return __hip_atomic_load((float*)p_, __ATOMIC_RELAXED, __HIP_MEMORY_SCOPE_AGENT);
}
__device__ __forceinline__ void astore(float* p_, float v) {
    __hip_atomic_store(p_, v, __ATOMIC_RELAXED, __HIP_MEMORY_SCOPE_AGENT);
}
__device__ __forceinline__ unsigned au_add(unsigned* p_, unsigned v) {
    return __hip_atomic_fetch_add(p_, v, __ATOMIC_RELAXED, __HIP_MEMORY_SCOPE_AGENT);
}
__device__ __forceinline__ unsigned au_load(const unsigned* p_) {
    return __hip_atomic_load((unsigned*)p_, __ATOMIC_RELAXED, __HIP_MEMORY_SCOPE_AGENT);
}
__device__ __forceinline__ void au_store(unsigned* p_, unsigned v) {
    __hip_atomic_store(p_, v, __ATOMIC_RELAXED, __HIP_MEMORY_SCOPE_AGENT);
}

// ---------------- two-level grid barrier (relaxed agent atomics, striped).
// Arrive: group counter (16 RMWs/line). Last of group arrives at root
// (64 RMWs), polls root, then releases its group; members poll group line.
// __syncthreads before arrive drains vmcnt -> this block's agent stores are
// LLC-visible before its arrive lands (ack-ordered on the same wave).
__device__ __forceinline__ void gsync(unsigned* barbase, int idx) {
    __syncthreads();
    if (threadIdx.x == 0) {
        unsigned* B = barbase + idx * BAR_STRIDE;
        const int bid = blockIdx.y * NBLK + blockIdx.x;
        const int grp = bid >> GRP_SHIFT;
        unsigned* gc   = B + grp * 32;
        unsigned* root = B + NGRP * 32;
        unsigned* gr   = B + NGRP * 32 + 32 + grp * 32;
        unsigned old = au_add(gc, 1u);
        if (old == GRP_SIZE - 1u) {
            unsigned r = au_add(root, 1u) + 1u;
            while (r < (unsigned)NGRP) {
                __builtin_amdgcn_s_sleep(4);
                r = au_load(root);
            }
            au_store(gr, 1u);
        } else {
            while (au_load(gr) == 0u)
                __builtin_amdgcn_s_sleep(4);
        }
        asm volatile("" ::: "memory");
    }
    __syncthreads();
}

__device__ __forceinline__ float fexp2(float x) {
#if __has_builtin(__builtin_amdgcn_exp2f)
    return __builtin_amdgcn_exp2f(x);
#else
    return exp2f(x);
#endif
}
__device__ __forceinline__ float fsqrt(float x) {
#if __has_builtin(__builtin_amdgcn_sqrtf)
    return __builtin_amdgcn_sqrtf(x);
#else
    return __sqrtf(x);
#endif
}

__device__ __forceinline__ float wave_reduce(float v) {
    v += __shfl_xor(v, 32);
    v += __shfl_xor(v, 16);
    v += __shfl_xor(v, 8);
    v += __shfl_xor(v, 4);
    v += __shfl_xor(v, 2);
    v += __shfl_xor(v, 1);
    return v;
}

// ---------------------------------------------------------------- phase: sweep-0 ratioL
// remainR == 1 implicitly. Writes ratioL[0] (agent), remainL = 1 (private).
__device__ __forceinline__ void phase_ratioL0(Smem& sm, const Params& p, float ls2,
                                              float* __restrict__ rLout) {
    const int b = blockIdx.y;
    const int tid = threadIdx.x;
    const int wave = tid >> 6;
    const int lane = tid & 63;
    const int row0 = blockIdx.x * RPB + wave * RPW;

    const float* x1 = p.xyz1 + b * 3 * NPTS;
    const float* x2 = p.xyz2 + b * 3 * NPTS;
    const float2* x2x = (const float2*)(x2);
    const float2* x2y = (const float2*)(x2 + NPTS);
    const float2* x2z = (const float2*)(x2 + 2 * NPTS);

    float px[RPW], py[RPW], pz[RPW];
    v2f acc[RPW];
#pragma unroll
    for (int r = 0; r < RPW; ++r) {
        px[r] = x1[row0 + r];
        py[r] = x1[NPTS + row0 + r];
        pz[r] = x1[2 * NPTS + row0 + r];
        acc[r] = (v2f)(0.0f);
    }
    for (int c0 = 0; c0 < NPTS; c0 += TILE) {
        __syncthreads();
        for (int i = tid; i < TILE / 2; i += THREADS) {
            int e = c0 / 2 + i;
            float2 xx = x2x[e], yy = x2y[e];
            sm.sA[i] = make_float4(xx.x, xx.y, yy.x, yy.y);
            sm.sC[i] = x2z[e];
        }
        __syncthreads();
#pragma unroll 2
        for (int j = 0; j < TILE / 128; ++j) {
            float4 a = sm.sA[lane + 64 * j];
            float2 z = sm.sC[lane + 64 * j];
            v2f ax = {a.x, a.y}, ay = {a.z, a.w}, az = {z.x, z.y};
#pragma unroll
            for (int r = 0; r < RPW; ++r) {
                v2f dx = px[r] - ax, dy = py[r] - ay, dz = pz[r] - az;
                v2f d = dx * dx + dy * dy + dz * dz;
                v2f sd = ls2 * d;
                if (!__all(fmaxf(sd.x, sd.y) < CULL_FULL)) {
                    v2f e2 = {fexp2(sd.x), fexp2(sd.y)};
                    acc[r] += e2;
                }
            }
        }
    }
#pragma unroll
    for (int r = 0; r < RPW; ++r) {
        float s = wave_reduce(acc[r].x + acc[r].y);
        if (lane == 0) {
            int idx = b * NPTS + row0 + r;
            astore(&rLout[idx], 1.0f / (EMD_EPS + s));
            p.remainL[idx] = 1.0f;
        }
    }
}

// ---------------------------------------------------------------- phase: ratioR (sweep t)
// Stages x1 + ratioL[t] (normal loads). rRprev == nullptr means remainR == 1.
template <bool CULL>
__device__ __forceinline__ void phase_ratioR(Smem& sm, const Params& p, float ls2,
                                             const float* __restrict__ rL,
                                             const float* __restrict__ rRprev,
                                             float* __restrict__ rRout,
                                             float* __restrict__ remROut) {
    const int b = blockIdx.y;
    const int tid = threadIdx.x;
    const int wave = tid >> 6;
    const int lane = tid & 63;
    const int col0 = blockIdx.x * RPB + wave * RPW;

    const float* x1 = p.xyz1 + b * 3 * NPTS;
    const float* x2 = p.xyz2 + b * 3 * NPTS;
    const float2* x1x = (const float2*)(x1);
    const float2* x1y = (const float2*)(x1 + NPTS);
    const float2* x1z = (const float2*)(x1 + 2 * NPTS);
    const float2* wLv = (const float2*)(rL + b * NPTS);

    float px[RPW], py[RPW], pz[RPW];
    v2f acc[RPW];
#pragma unroll
    for (int r = 0; r < RPW; ++r) {
        px[r] = x2[col0 + r];
        py[r] = x2[NPTS + col0 + r];
        pz[r] = x2[2 * NPTS + col0 + r];
        acc[r] = (v2f)(0.0f);
    }
    for (int c0 = 0; c0 < NPTS; c0 += TILE) {
        __syncthreads();
        for (int i = tid; i < TILE / 2; i += THREADS) {
            int e = c0 / 2 + i;
            float2 xx = x1x[e], yy = x1y[e], zz = x1z[e], ww = wLv[e];
            sm.sA[i] = make_float4(xx.x, xx.y, yy.x, yy.y);
            sm.sB[i] = make_float4(zz.x, zz.y, ww.x, ww.y);
        }
        __syncthreads();
#pragma unroll 2
        for (int j = 0; j < TILE / 128; ++j) {
            float4 a = sm.sA[lane + 64 * j];
            float4 bq = sm.sB[lane + 64 * j];
            v2f ax = {a.x, a.y}, ay = {a.z, a.w};
            v2f az = {bq.x, bq.y}, aw = {bq.z, bq.w};
#pragma unroll
            for (int r = 0; r < RPW; ++r) {
                v2f dx = px[r] - ax, dy = py[r] - ay, dz = pz[r] - az;
                v2f d = dx * dx + dy * dy + dz * dz;
                v2f sd = ls2 * d;
                bool live = true;
                if (CULL) live = !__all(fmaxf(sd.x, sd.y) < CULL_FULL);
                if (live) {
                    v2f e2 = {fexp2(sd.x), fexp2(sd.y)};
                    acc[r] += e2 * aw;
                }
            }
        }
    }
#pragma unroll
    for (int r = 0; r < RPW; ++r) {
        float s = wave_reduce(acc[r].x + acc[r].y);
        if (lane == 0) {
            int idx = b * NPTS + col0 + r;
            // remainR[t-1][idx] was normal-read by every XCD during cost-phase
            // t-1 staging -> L2-clean-correct here; t==0 is the implicit 1.0.
            float rv = rRprev ? rRprev[idx] : 1.0f;
            float sumr = rv * s;
            float cons = fminf(rv / (sumr + EMD_EPS), 1.0f);
            astore(&rRout[idx], cons * rv);
            astore(&remROut[idx], fmaxf(0.0f, rv - sumr));
        }
    }
}

// ---------------------------------------------------------------- phase: cost(t) + ratioL(t+1)
// Stages x2 + ratioR[t] + remainR[t] (normal loads; fresh buffers this sweep).
template <bool SQ, bool CULL>
__device__ __forceinline__ void phase_cost(Smem& sm, const Params& p,
                                           float ls2, float ls2n,
                                           const float* __restrict__ rR,
                                           const float* __restrict__ w2,
                                           const float* __restrict__ rLin,
                                           float* __restrict__ rLout,
                                           int initCost) {
    const int b = blockIdx.y;
    const int tid = threadIdx.x;
    const int wave = tid >> 6;
    const int lane = tid & 63;
    const int row0 = blockIdx.x * RPB + wave * RPW;

    const float* x1 = p.xyz1 + b * 3 * NPTS;
    const float* x2 = p.xyz2 + b * 3 * NPTS;
    const float2* x2x = (const float2*)(x2);
    const float2* x2y = (const float2*)(x2 + NPTS);
    const float2* x2z = (const float2*)(x2 + 2 * NPTS);
    const float2* wRv = (const float2*)(rR + b * NPTS);
    const float2* w2v = (const float2*)(w2 + b * NPTS);

    float px[RPW], py[RPW], pz[RPW];
    v2f acc_a[RPW], acc_c[RPW], acc_s[RPW];
#pragma unroll
    for (int r = 0; r < RPW; ++r) {
        px[r] = x1[row0 + r];
        py[r] = x1[NPTS + row0 + r];
        pz[r] = x1[2 * NPTS + row0 + r];
        acc_a[r] = (v2f)(0.0f);
        acc_c[r] = (v2f)(0.0f);
        acc_s[r] = (v2f)(0.0f);
    }
    for (int c0 = 0; c0 < NPTS; c0 += TILE) {
        __syncthreads();
        for (int i = tid; i < TILE / 2; i += THREADS) {
            int e = c0 / 2 + i;
            float2 xx = x2x[e], yy = x2y[e], zz = x2z[e];
            float2 wr = wRv[e];
            float2 cw = w2v[e];
            sm.sA[i] = make_float4(xx.x, xx.y, yy.x, yy.y);
            sm.sB[i] = make_float4(zz.x, zz.y, wr.x, wr.y);
            sm.sC[i] = cw;
        }
        __syncthreads();
#pragma unroll 2
        for (int j = 0; j < TILE / 128; ++j) {
            float4 a = sm.sA[lane + 64 * j];
            float4 bq = sm.sB[lane + 64 * j];
            float2 c = sm.sC[lane + 64 * j];
            v2f ax = {a.x, a.y}, ay = {a.z, a.w};
            v2f az = {bq.x, bq.y}, wr = {bq.z, bq.w};
            v2f cw = {c.x, c.y};
#pragma unroll
            for (int r = 0; r < RPW; ++r) {
                v2f dx = px[r] - ax, dy = py[r] - ay, dz = pz[r] - az;
                v2f d = dx * dx + dy * dy + dz * dz;
                if (SQ) {
                    v2f sd = ls2n * d;
                    bool fullskip = false, partskip = false;
                    if (CULL) {
                        float mx = fmaxf(sd.x, sd.y);
                        fullskip = __all(mx < CULL_FULL);
                        partskip = __all(mx < CULL_PART);
                    }
                    if (!fullskip) {
                        v2f e2 = {fexp2(sd.x), fexp2(sd.y)};
                        acc_s[r] += e2 * cw;
                        if (!partskip) {
                            v2f e4 = e2 * e2;
                            v2f er = (e4 * e4) * wr;
                            acc_a[r] += er;
                            v2f sq = {fsqrt(d.x), fsqrt(d.y)};
                            acc_c[r] += er * sq;
                        }
                    }
                } else {
                    v2f sd = ls2 * d;
                    v2f e1 = {fexp2(sd.x), fexp2(sd.y)};
                    v2f er = e1 * wr;
                    acc_s[r] += cw;   // e2 == 1 when ls2n == 0
                    acc_a[r] += er;
                    v2f sq = {fsqrt(d.x), fsqrt(d.y)};
                    acc_c[r] += er * sq;
                }
            }
        }
    }
    float wcost = 0.0f;
#pragma unroll
    for (int r = 0; r < RPW; ++r) {
        float sa = wave_reduce(acc_a[r].x + acc_a[r].y);
        float sc = wave_reduce(acc_c[r].x + acc_c[r].y);
        float ss = wave_reduce(acc_s[r].x + acc_s[r].y);
        if (lane == 0) {
            int idx = b * NPTS + row0 + r;
            float rl = rLin[idx];                       // L2 (staged this sweep)
            float rem = fmaxf(0.0f, p.remainL[idx] - rl * sa);   // private
            p.remainL[idx] = rem;
            astore(&rLout[idx], rem / (EMD_EPS + ss));  // next sweep's ratioL
            wcost = fmaf(rl, sc, wcost);
        }
    }
    if (lane == 0) sm.s_cost[wave] = wcost;
    __syncthreads();
    if (tid == 0) {
        float t = sm.s_cost[0] + sm.s_cost[1] + sm.s_cost[2] + sm.s_cost[3];
        int ci = b * NBLK + blockIdx.x;
        astore(&p.cost_part[ci], initCost ? t : aload(&p.cost_part[ci]) + t);
    }
}

// ---------------------------------------------------------------- phase: sum ratioL[9]
__device__ __forceinline__ void phase_sum_ratioL(Smem& sm, const Params& p,
                                                 const float* __restrict__ rL) {
    if (blockIdx.x != 0) return;
    const int b = blockIdx.y;
    const int tid = threadIdx.x;
    float s = 0.0f;
    for (int i = tid; i < NPTS; i += 256) s += rL[b * NPTS + i];
    s = wave_reduce(s);
    if ((tid & 63) == 0) sm.s_cost[tid >> 6] = s;
    __syncthreads();
    if (tid == 0)
        astore(&p.S_L[b], sm.s_cost[0] + sm.s_cost[1] + sm.s_cost[2] + sm.s_cost[3]);
}

// ---------------------------------------------------------------- phase: level-0 cost
__device__ __forceinline__ void phase_cost_l0(Smem& sm, const Params& p,
                                              const float* __restrict__ w2,
                                              const float* __restrict__ rL) {
    const int b = blockIdx.y;
    const int tid = threadIdx.x;
    const int wave = tid >> 6;
    const int lane = tid & 63;
    const int row0 = blockIdx.x * RPB + wave * RPW;
    const float sL = aload(&p.S_L[b]);

    const float* x1 = p.xyz1 + b * 3 * NPTS;
    const float* x2 = p.xyz2 + b * 3 * NPTS;
    const float2* x2x = (const float2*)(x2);
    const float2* x2y = (const float2*)(x2 + NPTS);
    const float2* x2z = (const float2*)(x2 + 2 * NPTS);
    const float2* wRv = (const float2*)(w2 + b * NPTS);

    float px[RPW], py[RPW], pz[RPW];
    v2f acc_c[RPW];
#pragma unroll
    for (int r = 0; r < RPW; ++r) {
        px[r] = x1[row0 + r];
        py[r] = x1[NPTS + row0 + r];
        pz[r] = x1[2 * NPTS + row0 + r];
        acc_c[r] = (v2f)(0.0f);
    }
    for (int c0 = 0; c0 < NPTS; c0 += TILE) {
        __syncthreads();
        for (int i = tid; i < TILE / 2; i += THREADS) {
            int e = c0 / 2 + i;
            float2 xx = x2x[e], yy = x2y[e], zz = x2z[e], rv = wRv[e];
            float wr0 = fminf(rv.x / (rv.x * sL + EMD_EPS), 1.0f) * rv.x;
            float wr1 = fminf(rv.y / (rv.y * sL + EMD_EPS), 1.0f) * rv.y;
            sm.sA[i] = make_float4(xx.x, xx.y, yy.x, yy.y);
            sm.sB[i] = make_float4(zz.x, zz.y, wr0, wr1);
        }
        __syncthreads();
#pragma unroll 2
        for (int j = 0; j < TILE / 128; ++j) {
            float4 a = sm.sA[lane + 64 * j];
            float4 bq = sm.sB[lane + 64 * j];
            v2f ax = {a.x, a.y}, ay = {a.z, a.w};
            v2f az = {bq.x, bq.y}, wr = {bq.z, bq.w};
#pragma unroll
            for (int r = 0; r < RPW; ++r) {
                v2f dx = px[r] - ax, dy = py[r] - ay, dz = pz[r] - az;
                v2f d = dx * dx + dy * dy + dz * dz;
                v2f sq = {fsqrt(d.x), fsqrt(d.y)};
                acc_c[r] += wr * sq;
            }
        }
    }
    float wcost = 0.0f;
#pragma unroll
    for (int r = 0; r < RPW; ++r) {
        float sc = wave_reduce(acc_c[r].x + acc_c[r].y);
        if (lane == 0)
            wcost = fmaf(rL[b * NPTS + row0 + r], sc, wcost);
    }
    if (lane == 0) sm.s_cost[wave] = wcost;
    __syncthreads();
    if (tid == 0) {
        float t = sm.s_cost[0] + sm.s_cost[1] + sm.s_cost[2] + sm.s_cost[3];
        int ci = b * NBLK + blockIdx.x;
        astore(&p.cost_part[ci], aload(&p.cost_part[ci]) + t);
    }
}

// ---------------------------------------------------------------- phase: finalize
__device__ __forceinline__ void phase_final(Smem& sm, const Params& p) {
    if (blockIdx.x != 0 || blockIdx.y != 0) return;
    const int tid = threadIdx.x;
    float s = 0.0f;
    for (int i = tid; i < BATCH * NBLK; i += 256) s += aload(&p.cost_part[i]);
    s = wave_reduce(s);
    if ((tid & 63) == 0) sm.s_cost[tid >> 6] = s;
    __syncthreads();
    if (tid == 0)
        p.out[0] = (sm.s_cost[0] + sm.s_cost[1] + sm.s_cost[2] + sm.s_cost[3]) /
                   ((float)NPTS * (float)BATCH);
}

// ---------------------------------------------------------------- unified persistent kernel
__global__ __launch_bounds__(THREADS, 4) void k_emd_all(Params p) {
    __shared__ Smem sm;
    int bi = 0;
    phase_ratioL0(sm, p, p.ls2[0], p.ratioL[0]);
    gsync(p.bar, bi++);
    for (int t = 0; t < 9; ++t) {
        const float* rRprev = (t == 0) ? nullptr : p.remainR[t - 1];
        if (t < 4)
            phase_ratioR<true>(sm, p, p.ls2[t], p.ratioL[t], rRprev,
                               p.ratioR[t], p.remainR[t]);
        else
            phase_ratioR<false>(sm, p, p.ls2[t], p.ratioL[t], rRprev,
                                p.ratioR[t], p.remainR[t]);
        gsync(p.bar, bi++);
        if (t < 4)
            phase_cost<true, true>(sm, p, p.ls2[t], p.ls2[t + 1], p.ratioR[t],
                                   p.remainR[t], p.ratioL[t], p.ratioL[t + 1], t == 0);
        else if (t < 8)
            phase_cost<true, false>(sm, p, p.ls2[t], p.ls2[t + 1], p.ratioR[t],
                                    p.remainR[t], p.ratioL[t], p.ratioL[t + 1], 0);
        else
            phase_cost<false, false>(sm, p, p.ls2[8], 0.0f, p.ratioR[8],
                                     p.remainR[8], p.ratioL[8], p.ratioL[9], 0);
        gsync(p.bar, bi++);
    }
    phase_sum_ratioL(sm, p, p.ratioL[9]);
    gsync(p.bar, bi++);
    phase_cost_l0(sm, p, p.remainR[8], p.ratioL[9]);
    gsync(p.bar, bi++);
    phase_final(sm, p);
}

// ---------------------------------------------------------------- barrier init
__global__ void k_zero(unsigned* bar) {
    const int n = NB_BAR * BAR_STRIDE;
    for (int i = blockIdx.x * 256 + threadIdx.x; i < n; i += gridDim.x * 256)
        __hip_atomic_store(&bar[i], 0u, __ATOMIC_RELAXED, __HIP_MEMORY_SCOPE_AGENT);
}

// ---------------------------------------------------------------- fallback wrappers
__global__ __launch_bounds__(THREADS, 4) void kw_ratioL0(Params p) {
    __shared__ Smem sm;
    phase_ratioL0(sm, p, p.ls2[0], p.ratioL[0]);
}
__global__ __launch_bounds__(THREADS, 4) void kw_ratioR(Params p, int t) {
    __shared__ Smem sm;
    const float* rRprev = (t == 0) ? nullptr : p.remainR[t - 1];
    if (t < 4) phase_ratioR<true>(sm, p, p.ls2[t], p.ratioL[t], rRprev,
                                  p.ratioR[t], p.remainR[t]);
    else       phase_ratioR<false>(sm, p, p.ls2[t], p.ratioL[t], rRprev,
                                   p.ratioR[t], p.remainR[t]);
}
__global__ __launch_bounds__(THREADS, 4) void kw_cost(Params p, int t) {
    __shared__ Smem sm;
    if (t < 4)
        phase_cost<true, true>(sm, p, p.ls2[t], p.ls2[t + 1], p.ratioR[t],
                               p.remainR[t], p.ratioL[t], p.ratioL[t + 1], t == 0);
    else if (t < 8)
        phase_cost<true, false>(sm, p, p.ls2[t], p.ls2[t + 1], p.ratioR[t],
                                p.remainR[t], p.ratioL[t], p.ratioL[t + 1], 0);
    else
        phase_cost<false, false>(sm, p, p.ls2[8], 0.0f, p.ratioR[8],
                                 p.remainR[8], p.ratioL[8], p.ratioL[9], 0);
}
__global__ __launch_bounds__(THREADS, 4) void kw_sum(Params p) {
    __shared__ Smem sm;
    phase_sum_ratioL(sm, p, p.ratioL[9]);
}
__global__ __launch_bounds__(THREADS, 4) void kw_cost_l0(Params p) {
    __shared__ Smem sm;
    phase_cost_l0(sm, p, p.remainR[8], p.ratioL[9]);
}
__global__ __launch_bounds__(THREADS, 4) void kw_final(Params p) {
    __shared__ Smem sm;
    phase_final(sm, p);
}

extern "C" void kernel_launch(void* const* d_in, const int* in_sizes, int n_in,
                              void* d_out, int out_size, void* d_ws, size_t ws_size,
                              hipStream_t stream) {
    Params p;
    p.xyz1 = (const float*)d_in[0];
    p.xyz2 = (const float*)d_in[1];
    const int BN = BATCH * NPTS;              // 16384 floats per buffer
    const int BUF = BN + 1024;                // + 4KB pad between buffers
    float* ws = (float*)d_ws;
    p.remainL   = ws;                         // BN, block-private
    p.cost_part = ws + BN;                    // 1024
    p.S_L       = p.cost_part + 2048;         // BATCH
    p.bar       = (unsigned*)(p.S_L + 256);   // NB_BAR * BAR_STRIDE u32
    float* vbase = (float*)(p.bar + NB_BAR * BAR_STRIDE) + 256;
    for (int t = 0; t < 10; ++t) p.ratioL[t]  = vbase + t * BUF;
    for (int t = 0; t < 9; ++t)  p.ratioR[t]  = vbase + (10 + t) * BUF;
    for (int t = 0; t < 9; ++t)  p.remainR[t] = vbase + (19 + t) * BUF;
    p.out = (float*)d_out;

    static const double levels[10] = {
        -16384.0, -4096.0, -1024.0, -256.0, -64.0,
        -16.0, -4.0, -1.0, -0.25, 0.0};
    for (int t = 0; t < 10; ++t)
        p.ls2[t] = (float)(levels[t] * 1.4426950408889634);

    dim3 grid(NBLK, BATCH), blk(THREADS);

    static int coop_ok = -1;
    if (coop_ok < 0) {
        int v = 0;
        hipDeviceGetAttribute(&v, hipDeviceAttributeCooperativeLaunch, 0);
        coop_ok = v;
    }

    hipError_t err = hipErrorUnknown;
    if (coop_ok) {
        k_zero<<<64, 256, 0, stream>>>(p.bar);
        void* args[] = {(void*)&p};
        err = hipLaunchCooperativeKernel((void*)k_emd_all, grid, blk, args, 0, stream);
    }
    if (err != hipSuccess) {
        kw_ratioL0<<<grid, blk, 0, stream>>>(p);
        for (int t = 0; t < 9; ++t) {
            kw_ratioR<<<grid, blk, 0, stream>>>(p, t);
            kw_cost<<<grid, blk, 0, stream>>>(p, t);
        }
        kw_sum<<<dim3(1, BATCH), blk, 0, stream>>>(p);
        kw_cost_l0<<<grid, blk, 0, stream>>>(p);
        kw_final<<<dim3(1, 1), blk, 0, stream>>>(p);
    }
}